// Round 2
// baseline (564.355 us; speedup 1.0000x reference)
//
#include <hip/hip_runtime.h>
#include <hip/hip_bf16.h>
#include <math.h>

// Problem constants: B=2, L=512, D=1024, H=16, DH=64. N = B*L = 1024.

typedef unsigned short ushort_t;
typedef __attribute__((ext_vector_type(8))) short bf16x8;
typedef __attribute__((ext_vector_type(4))) float f32x4;

__device__ __forceinline__ float sigmoidf_(float z) { return 1.f / (1.f + expf(-z)); }

__device__ __forceinline__ ushort_t f2bf(float f) {
    __hip_bfloat16 h = __float2bfloat16(f);
    return *reinterpret_cast<ushort_t*>(&h);
}

// ---------------------------------------------------------------------------
// Convert 5 fp32 1M-element arrays to bf16 (x, q1w, k1w, k2w, cpw).
// grid = 2560 blocks * 256 threads, 8 elements/thread.
// ---------------------------------------------------------------------------
__global__ __launch_bounds__(256) void cvt5(const float* __restrict__ s0, const float* __restrict__ s1,
                                            const float* __restrict__ s2, const float* __restrict__ s3,
                                            const float* __restrict__ s4,
                                            ushort_t* __restrict__ d0, ushort_t* __restrict__ d1,
                                            ushort_t* __restrict__ d2, ushort_t* __restrict__ d3,
                                            ushort_t* __restrict__ d4) {
    const int t = blockIdx.x * 256 + threadIdx.x;   // 0..655359
    const int arr = t >> 17;                         // 131072 threads per array
    const int off = (t & 131071) * 8;
    const float* s = arr == 0 ? s0 : arr == 1 ? s1 : arr == 2 ? s2 : arr == 3 ? s3 : s4;
    ushort_t* d = arr == 0 ? d0 : arr == 1 ? d1 : arr == 2 ? d2 : arr == 3 ? d3 : d4;
    float4 a = *reinterpret_cast<const float4*>(s + off);
    float4 b = *reinterpret_cast<const float4*>(s + off + 4);
    union { uint4 v; ushort_t u[8]; } pk;
    pk.u[0] = f2bf(a.x); pk.u[1] = f2bf(a.y); pk.u[2] = f2bf(a.z); pk.u[3] = f2bf(a.w);
    pk.u[4] = f2bf(b.x); pk.u[5] = f2bf(b.y); pk.u[6] = f2bf(b.z); pk.u[7] = f2bf(b.w);
    *reinterpret_cast<uint4*>(d + off) = pk.v;
}

__global__ __launch_bounds__(256) void cvt1(const float* __restrict__ s, ushort_t* __restrict__ d) {
    const int off = (blockIdx.x * 256 + threadIdx.x) * 8;
    float4 a = *reinterpret_cast<const float4*>(s + off);
    float4 b = *reinterpret_cast<const float4*>(s + off + 4);
    union { uint4 v; ushort_t u[8]; } pk;
    pk.u[0] = f2bf(a.x); pk.u[1] = f2bf(a.y); pk.u[2] = f2bf(a.z); pk.u[3] = f2bf(a.w);
    pk.u[4] = f2bf(b.x); pk.u[5] = f2bf(b.y); pk.u[6] = f2bf(b.z); pk.u[7] = f2bf(b.w);
    *reinterpret_cast<uint4*>(d + off) = pk.v;
}

// ---------------------------------------------------------------------------
// bf16 MFMA GEMM: Out[sel][1024,1024] = A @ W[sel] + bias[sel] (fp32 out).
// 64x64 tile, BK=64, 256 threads = 4 waves, each wave 16 rows x 64 cols.
// grid (16, 16, nsel). A is bf16 [1024][1024]; W bf16 [K][N] row-major.
// ---------------------------------------------------------------------------
__global__ __launch_bounds__(256) void gemm_mfma(const ushort_t* __restrict__ Ab,
                                                 const ushort_t* __restrict__ W0,
                                                 const ushort_t* __restrict__ W1,
                                                 const ushort_t* __restrict__ W2,
                                                 const float* __restrict__ b0,
                                                 const float* __restrict__ b1,
                                                 const float* __restrict__ b2,
                                                 float* __restrict__ O0,
                                                 float* __restrict__ O1,
                                                 float* __restrict__ O2) {
    const int sel = blockIdx.z;
    const ushort_t* Wb = sel == 0 ? W0 : sel == 1 ? W1 : W2;
    const float* bias = sel == 0 ? b0 : sel == 1 ? b1 : b2;
    float* Out = sel == 0 ? O0 : sel == 1 ? O1 : O2;
    const int m0 = blockIdx.y * 64, n0 = blockIdx.x * 64;

    __shared__ ushort_t As[64][72];   // [m][k], +8 pad
    __shared__ ushort_t Bs[64][72];   // [n][k] (transposed), +8 pad

    const int tid = threadIdx.x;
    const int wave = tid >> 6, lane = tid & 63;
    const int l15 = lane & 15, lq = lane >> 4;

    const int arow = tid >> 2;          // 0..63
    const int ak = (tid & 3) * 16;      // 0,16,32,48
    const int bk = tid >> 2;            // 0..63 (k within tile)
    const int bn = (tid & 3) * 16;      // 0,16,32,48

    f32x4 acc[4];
#pragma unroll
    for (int i = 0; i < 4; ++i) acc[i] = (f32x4){0.f, 0.f, 0.f, 0.f};

    for (int k0 = 0; k0 < 1024; k0 += 64) {
        uint4 av0 = *reinterpret_cast<const uint4*>(Ab + (size_t)(m0 + arow) * 1024 + k0 + ak);
        uint4 av1 = *reinterpret_cast<const uint4*>(Ab + (size_t)(m0 + arow) * 1024 + k0 + ak + 8);
        union { uint4 v; ushort_t u[8]; } bu0, bu1;
        bu0.v = *reinterpret_cast<const uint4*>(Wb + (size_t)(k0 + bk) * 1024 + n0 + bn);
        bu1.v = *reinterpret_cast<const uint4*>(Wb + (size_t)(k0 + bk) * 1024 + n0 + bn + 8);
        __syncthreads();  // previous iteration's LDS reads done
        *reinterpret_cast<uint4*>(&As[arow][ak]) = av0;
        *reinterpret_cast<uint4*>(&As[arow][ak + 8]) = av1;
#pragma unroll
        for (int j = 0; j < 8; ++j) Bs[bn + j][bk] = bu0.u[j];
#pragma unroll
        for (int j = 0; j < 8; ++j) Bs[bn + 8 + j][bk] = bu1.u[j];
        __syncthreads();

#pragma unroll
        for (int kk = 0; kk < 64; kk += 32) {
            bf16x8 a = *reinterpret_cast<const bf16x8*>(&As[16 * wave + l15][kk + 8 * lq]);
#pragma unroll
            for (int nt = 0; nt < 4; ++nt) {
                bf16x8 b = *reinterpret_cast<const bf16x8*>(&Bs[16 * nt + l15][kk + 8 * lq]);
                acc[nt] = __builtin_amdgcn_mfma_f32_16x16x32_bf16(a, b, acc[nt], 0, 0, 0);
            }
        }
    }

#pragma unroll
    for (int nt = 0; nt < 4; ++nt) {
        const int col = n0 + 16 * nt + l15;
        const float bcol = bias[col];
#pragma unroll
        for (int r = 0; r < 4; ++r) {
            const int row = m0 + 16 * wave + 4 * lq + r;
            Out[(size_t)row * 1024 + col] = acc[nt][r] + bcol;
        }
    }
}

// ---------------------------------------------------------------------------
// Gate scan (unchanged): per (b,h), Gc and a = silu(K.sw)/Gc.
// ---------------------------------------------------------------------------
__global__ __launch_bounds__(64) void scan_kernel(const float* __restrict__ x,
                                                  const float* __restrict__ Kb,
                                                  const float* __restrict__ gw_w,
                                                  const float* __restrict__ gw_b,
                                                  const float* __restrict__ sw_w,
                                                  const float* __restrict__ sw_b,
                                                  float* __restrict__ gc,
                                                  float* __restrict__ ab) {
    const int bh = blockIdx.x;
    const int b = bh >> 4, h = bh & 15;
    const int lane = threadIdx.x;

    __shared__ float gww[64], sww[64];
    gww[lane] = gw_w[lane];
    sww[lane] = sw_w[lane];
    __syncthreads();
    const float gwb = gw_b[0], swb = sw_b[0];

    float carry = 0.f;
    for (int c = 0; c < 8; ++c) {
        const int t = c * 64 + lane;
        const float* xr = x + (size_t)(b * 512 + t) * 1024 + h * 64;
        const float* kr = Kb + (size_t)(b * 512 + t) * 1024 + h * 64;
        float dg = 0.f, dk = 0.f;
#pragma unroll
        for (int d = 0; d < 64; d += 4) {
            float4 xv = *reinterpret_cast<const float4*>(xr + d);
            float4 kv = *reinterpret_cast<const float4*>(kr + d);
            dg += xv.x * gww[d] + xv.y * gww[d + 1] + xv.z * gww[d + 2] + xv.w * gww[d + 3];
            dk += kv.x * sww[d] + kv.y * sww[d + 1] + kv.z * sww[d + 2] + kv.w * sww[d + 3];
        }
        const float g = sigmoidf_(dg + gwb);
        float lg = logf(fmaxf(g, 1e-6f));
        float ps = lg;
#pragma unroll
        for (int off = 1; off < 64; off <<= 1) {
            float v = __shfl_up(ps, off, 64);
            if (lane >= off) ps += v;
        }
        const float lsum = carry + ps;
        const float lclip = fminf(fmaxf(lsum, -30.f), 30.f);
        const float Gc = expf(lclip) + 1e-6f;
        const float z = dk + swb;
        const float R = z * sigmoidf_(z);
        gc[bh * 512 + t] = Gc;
        ab[bh * 512 + t] = R / Gc;
        carry += __shfl(ps, 63, 64);
    }
}

// ---------------------------------------------------------------------------
// Balanced causal linear-attention: one block per (bh, rt, jt), jt <= rt.
// grid = 32 * 36 = 1152 blocks, 256 threads.
// MODE 0: atomicAdd O1 += Gc[r] * S_tile @ (a*V);  O1 pre-zeroed.
// MODE 1: atomicAdd Yt[t'+1] += q2K2-scores @ E;   Yt pre-initialized to O1.
// ---------------------------------------------------------------------------
template <int MODE>
__global__ __launch_bounds__(256) void attn_kernel(const float* __restrict__ x,
                                                   const float* __restrict__ Qb,
                                                   const float* __restrict__ Kb,
                                                   const float* __restrict__ C2,
                                                   const float* __restrict__ O1,
                                                   const float* __restrict__ gc,
                                                   const float* __restrict__ ab,
                                                   float* __restrict__ Out) {
    const int bh = blockIdx.x / 36;
    const int rem = blockIdx.x % 36;
    int rt = 0;
    while ((rt + 1) * (rt + 2) / 2 <= rem) ++rt;
    const int jt = rem - rt * (rt + 1) / 2;

    const int b = bh >> 4, h = bh & 15;
    const int r0 = rt * 64, c0 = jt * 64;
    const int tid = threadIdx.x;
    const int r = tid & 63;      // row within tile
    const int e0 = (tid >> 6) * 16;

    __shared__ float Qs[64][65];
    __shared__ float Ks[64][65];
    __shared__ float Vs[64][65];
    __shared__ float Ss[64][65];
    __shared__ float av[64];

    const size_t base = (size_t)(b * 512) * 1024 + h * 64;

    // stage Q tile (rows r0..r0+63)
    for (int idx = tid; idx < 1024; idx += 256) {
        const int rr = idx >> 4;
        const int c4 = (idx & 15) << 2;
        float4 qv = *reinterpret_cast<const float4*>(&Qb[base + (size_t)(r0 + rr) * 1024 + c4]);
        if (MODE == 1) {
            qv.x = (qv.x < 0.f ? qv.x : 0.02f * qv.x) * 0.125f;
            qv.y = (qv.y < 0.f ? qv.y : 0.02f * qv.y) * 0.125f;
            qv.z = (qv.z < 0.f ? qv.z : 0.02f * qv.z) * 0.125f;
            qv.w = (qv.w < 0.f ? qv.w : 0.02f * qv.w) * 0.125f;
        }
        Qs[rr][c4 + 0] = qv.x;
        Qs[rr][c4 + 1] = qv.y;
        Qs[rr][c4 + 2] = qv.z;
        Qs[rr][c4 + 3] = qv.w;
    }
    // stage K/V tile (cols c0..c0+63)
    for (int idx = tid; idx < 1024; idx += 256) {
        const int cc = idx >> 4;
        const int c4 = (idx & 15) << 2;
        const int tau = c0 + cc;
        float4 kv, vv;
        if (MODE == 0) {
            kv = *reinterpret_cast<const float4*>(&Kb[base + (size_t)tau * 1024 + c4]);
            vv = *reinterpret_cast<const float4*>(&x[base + (size_t)tau * 1024 + c4]);
        } else {
            if (tau <= 510) {
                float4 cv = *reinterpret_cast<const float4*>(&C2[base + (size_t)tau * 1024 + c4]);
                kv.x = sigmoidf_(cv.x * 6.25e-4f);
                kv.y = sigmoidf_(cv.y * 6.25e-4f);
                kv.z = sigmoidf_(cv.z * 6.25e-4f);
                kv.w = sigmoidf_(cv.w * 6.25e-4f);
                float4 xv = *reinterpret_cast<const float4*>(&x[base + (size_t)(tau + 1) * 1024 + c4]);
                float4 ov = *reinterpret_cast<const float4*>(&O1[base + (size_t)tau * 1024 + c4]);
                vv.x = xv.x - ov.x;
                vv.y = xv.y - ov.y;
                vv.z = xv.z - ov.z;
                vv.w = xv.w - ov.w;
            } else {
                kv.x = kv.y = kv.z = kv.w = 0.f;
                vv.x = vv.y = vv.z = vv.w = 0.f;
            }
        }
        Ks[cc][c4 + 0] = kv.x; Ks[cc][c4 + 1] = kv.y; Ks[cc][c4 + 2] = kv.z; Ks[cc][c4 + 3] = kv.w;
        Vs[cc][c4 + 0] = vv.x; Vs[cc][c4 + 1] = vv.y; Vs[cc][c4 + 2] = vv.z; Vs[cc][c4 + 3] = vv.w;
    }
    if (MODE == 0 && tid < 64) av[tid] = ab[bh * 512 + c0 + tid];
    __syncthreads();

    // phase A: scores S[r][c] for this wave's 16-col slice
    {
        float s[16] = {};
        for (int d = 0; d < 64; ++d) {
            const float qd = Qs[r][d];
#pragma unroll
            for (int cc = 0; cc < 16; ++cc) s[cc] += qd * Ks[e0 + cc][d];
        }
#pragma unroll
        for (int cc = 0; cc < 16; ++cc) {
            const int c = e0 + cc;
            float sv = s[cc];
            if (MODE == 0) sv *= av[c];
            if (jt == rt && c > r) sv = 0.f;  // causal mask (same-tile only)
            Ss[r][c] = sv;
        }
    }
    __syncthreads();

    // phase B: acc[e] = S[r][:] @ V[:][e0..e0+16)
    float acc[16] = {};
    for (int c = 0; c < 64; ++c) {
        const float sv = Ss[r][c];
#pragma unroll
        for (int ee = 0; ee < 16; ++ee) acc[ee] += sv * Vs[c][e0 + ee];
    }

    if (MODE == 0) {
        const float gcr = gc[bh * 512 + r0 + r];
#pragma unroll
        for (int ee = 0; ee < 16; ++ee)
            atomicAdd(&Out[base + (size_t)(r0 + r) * 1024 + e0 + ee], gcr * acc[ee]);
    } else {
        const int tp = r0 + r;
        if (tp <= 510) {
#pragma unroll
            for (int ee = 0; ee < 16; ++ee)
                atomicAdd(&Out[base + (size_t)(tp + 1) * 1024 + e0 + ee], acc[ee]);
        }
    }
}

// ---------------------------------------------------------------------------
extern "C" void kernel_launch(void* const* d_in, const int* in_sizes, int n_in,
                              void* d_out, int out_size, void* d_ws, size_t ws_size,
                              hipStream_t stream) {
    const float* x   = (const float*)d_in[0];
    const float* q1w = (const float*)d_in[1];
    const float* q1b = (const float*)d_in[2];
    const float* k1w = (const float*)d_in[3];
    const float* k1b = (const float*)d_in[4];
    const float* k2w = (const float*)d_in[5];
    const float* k2b = (const float*)d_in[6];
    const float* gww = (const float*)d_in[7];
    const float* gwb = (const float*)d_in[8];
    const float* sww = (const float*)d_in[9];
    const float* swb = (const float*)d_in[10];
    const float* cpw = (const float*)d_in[11];
    const float* cpb = (const float*)d_in[12];
    float* out = (float*)d_out;

    float* ws = (float*)d_ws;
    float* Q   = ws;                        // 1M floats
    float* K   = ws + 1048576;              // 1M
    float* C2  = ws + 2097152;              // 1M
    float* O1  = ws + 3145728;              // 1M
    float* Yt  = ws + 4194304;              // 1M
    float* gcb = ws + 5242880;              // 16K
    float* abb = ws + 5259264;              // 16K
    ushort_t* xb   = (ushort_t*)(ws + 5275648);   // 1M ushort = 512K floats
    ushort_t* wqb  = (ushort_t*)(ws + 5799936);   // 1M ushort
    ushort_t* wkb  = (ushort_t*)(ws + 6324224);
    ushort_t* wcb  = (ushort_t*)(ws + 6848512);
    ushort_t* wpb  = (ushort_t*)(ws + 7372800);
    ushort_t* ytb  = (ushort_t*)(ws + 7897088);
    // end: 8,421,376 floats = 33.7 MB

    cvt5<<<2560, 256, 0, stream>>>(x, q1w, k1w, k2w, cpw, xb, wqb, wkb, wcb, wpb);
    gemm_mfma<<<dim3(16, 16, 3), 256, 0, stream>>>(xb, wqb, wkb, wcb, q1b, k1b, k2b, Q, K, C2);
    scan_kernel<<<32, 64, 0, stream>>>(x, K, gww, gwb, sww, swb, gcb, abb);
    hipMemsetAsync(O1, 0, 4194304, stream);
    attn_kernel<0><<<1152, 256, 0, stream>>>(x, Q, K, C2, O1, gcb, abb, O1);
    hipMemcpyAsync(Yt, O1, 4194304, hipMemcpyDeviceToDevice, stream);
    attn_kernel<1><<<1152, 256, 0, stream>>>(x, Q, K, C2, O1, gcb, abb, Yt);
    cvt1<<<512, 256, 0, stream>>>(Yt, ytb);
    gemm_mfma<<<dim3(16, 16, 1), 256, 0, stream>>>(ytb, wpb, wpb, wpb, cpb, cpb, cpb, out, out, out);
}

// Round 3
// 107.321 us; speedup vs baseline: 5.2586x; 5.2586x over previous
//
#include <hip/hip_runtime.h>
#include <hip/hip_bf16.h>
#include <math.h>

// Problem constants: B=2, L=512, D=1024, H=16, DH=64. N = B*L = 1024.

typedef unsigned short ushort_t;
typedef __attribute__((ext_vector_type(8))) short bf16x8;
typedef __attribute__((ext_vector_type(4))) float f32x4;

__device__ __forceinline__ float sigmoidf_(float z) { return 1.f / (1.f + expf(-z)); }

__device__ __forceinline__ ushort_t f2bf(float f) {
    __hip_bfloat16 h = __float2bfloat16(f);
    return *reinterpret_cast<ushort_t*>(&h);
}

// ---------------------------------------------------------------------------
// Convert 5 fp32 1M-element arrays to bf16 (x, q1w, k1w, k2w, cpw).
// ---------------------------------------------------------------------------
__global__ __launch_bounds__(256) void cvt5(const float* __restrict__ s0, const float* __restrict__ s1,
                                            const float* __restrict__ s2, const float* __restrict__ s3,
                                            const float* __restrict__ s4,
                                            ushort_t* __restrict__ d0, ushort_t* __restrict__ d1,
                                            ushort_t* __restrict__ d2, ushort_t* __restrict__ d3,
                                            ushort_t* __restrict__ d4) {
    const int t = blockIdx.x * 256 + threadIdx.x;
    const int arr = t >> 17;
    const int off = (t & 131071) * 8;
    const float* s = arr == 0 ? s0 : arr == 1 ? s1 : arr == 2 ? s2 : arr == 3 ? s3 : s4;
    ushort_t* d = arr == 0 ? d0 : arr == 1 ? d1 : arr == 2 ? d2 : arr == 3 ? d3 : d4;
    float4 a = *reinterpret_cast<const float4*>(s + off);
    float4 b = *reinterpret_cast<const float4*>(s + off + 4);
    union { uint4 v; ushort_t u[8]; } pk;
    pk.u[0] = f2bf(a.x); pk.u[1] = f2bf(a.y); pk.u[2] = f2bf(a.z); pk.u[3] = f2bf(a.w);
    pk.u[4] = f2bf(b.x); pk.u[5] = f2bf(b.y); pk.u[6] = f2bf(b.z); pk.u[7] = f2bf(b.w);
    *reinterpret_cast<uint4*>(d + off) = pk.v;
}

__global__ __launch_bounds__(256) void cvt1(const float* __restrict__ s, ushort_t* __restrict__ d) {
    const int off = (blockIdx.x * 256 + threadIdx.x) * 8;
    float4 a = *reinterpret_cast<const float4*>(s + off);
    float4 b = *reinterpret_cast<const float4*>(s + off + 4);
    union { uint4 v; ushort_t u[8]; } pk;
    pk.u[0] = f2bf(a.x); pk.u[1] = f2bf(a.y); pk.u[2] = f2bf(a.z); pk.u[3] = f2bf(a.w);
    pk.u[4] = f2bf(b.x); pk.u[5] = f2bf(b.y); pk.u[6] = f2bf(b.z); pk.u[7] = f2bf(b.w);
    *reinterpret_cast<uint4*>(d + off) = pk.v;
}

// ---------------------------------------------------------------------------
// bf16 MFMA GEMM: Out[sel] = A @ W[sel] + bias[sel] (fp32 out). 64x64 tile.
// ---------------------------------------------------------------------------
__global__ __launch_bounds__(256) void gemm_mfma(const ushort_t* __restrict__ Ab,
                                                 const ushort_t* __restrict__ W0,
                                                 const ushort_t* __restrict__ W1,
                                                 const ushort_t* __restrict__ W2,
                                                 const float* __restrict__ b0,
                                                 const float* __restrict__ b1,
                                                 const float* __restrict__ b2,
                                                 float* __restrict__ O0,
                                                 float* __restrict__ O1,
                                                 float* __restrict__ O2) {
    const int sel = blockIdx.z;
    const ushort_t* Wb = sel == 0 ? W0 : sel == 1 ? W1 : W2;
    const float* bias = sel == 0 ? b0 : sel == 1 ? b1 : b2;
    float* Out = sel == 0 ? O0 : sel == 1 ? O1 : O2;
    const int m0 = blockIdx.y * 64, n0 = blockIdx.x * 64;

    __shared__ ushort_t As[64][72];
    __shared__ ushort_t Bs[64][72];

    const int tid = threadIdx.x;
    const int wave = tid >> 6, lane = tid & 63;
    const int l15 = lane & 15, lq = lane >> 4;

    const int arow = tid >> 2;
    const int ak = (tid & 3) * 16;
    const int bk = tid >> 2;
    const int bn = (tid & 3) * 16;

    f32x4 acc[4];
#pragma unroll
    for (int i = 0; i < 4; ++i) acc[i] = (f32x4){0.f, 0.f, 0.f, 0.f};

    for (int k0 = 0; k0 < 1024; k0 += 64) {
        uint4 av0 = *reinterpret_cast<const uint4*>(Ab + (size_t)(m0 + arow) * 1024 + k0 + ak);
        uint4 av1 = *reinterpret_cast<const uint4*>(Ab + (size_t)(m0 + arow) * 1024 + k0 + ak + 8);
        union { uint4 v; ushort_t u[8]; } bu0, bu1;
        bu0.v = *reinterpret_cast<const uint4*>(Wb + (size_t)(k0 + bk) * 1024 + n0 + bn);
        bu1.v = *reinterpret_cast<const uint4*>(Wb + (size_t)(k0 + bk) * 1024 + n0 + bn + 8);
        __syncthreads();
        *reinterpret_cast<uint4*>(&As[arow][ak]) = av0;
        *reinterpret_cast<uint4*>(&As[arow][ak + 8]) = av1;
#pragma unroll
        for (int j = 0; j < 8; ++j) Bs[bn + j][bk] = bu0.u[j];
#pragma unroll
        for (int j = 0; j < 8; ++j) Bs[bn + 8 + j][bk] = bu1.u[j];
        __syncthreads();

#pragma unroll
        for (int kk = 0; kk < 64; kk += 32) {
            bf16x8 a = *reinterpret_cast<const bf16x8*>(&As[16 * wave + l15][kk + 8 * lq]);
#pragma unroll
            for (int nt = 0; nt < 4; ++nt) {
                bf16x8 b = *reinterpret_cast<const bf16x8*>(&Bs[16 * nt + l15][kk + 8 * lq]);
                acc[nt] = __builtin_amdgcn_mfma_f32_16x16x32_bf16(a, b, acc[nt], 0, 0, 0);
            }
        }
    }

#pragma unroll
    for (int nt = 0; nt < 4; ++nt) {
        const int col = n0 + 16 * nt + l15;
        const float bcol = bias[col];
#pragma unroll
        for (int r = 0; r < 4; ++r) {
            const int row = m0 + 16 * wave + 4 * lq + r;
            Out[(size_t)row * 1024 + col] = acc[nt][r] + bcol;
        }
    }
}

// ---------------------------------------------------------------------------
// Gate scan: per (b,h), Gc and a = silu(K.sw)/Gc.
// ---------------------------------------------------------------------------
__global__ __launch_bounds__(64) void scan_kernel(const float* __restrict__ x,
                                                  const float* __restrict__ Kb,
                                                  const float* __restrict__ gw_w,
                                                  const float* __restrict__ gw_b,
                                                  const float* __restrict__ sw_w,
                                                  const float* __restrict__ sw_b,
                                                  float* __restrict__ gc,
                                                  float* __restrict__ ab) {
    const int bh = blockIdx.x;
    const int b = bh >> 4, h = bh & 15;
    const int lane = threadIdx.x;

    __shared__ float gww[64], sww[64];
    gww[lane] = gw_w[lane];
    sww[lane] = sw_w[lane];
    __syncthreads();
    const float gwb = gw_b[0], swb = sw_b[0];

    float carry = 0.f;
    for (int c = 0; c < 8; ++c) {
        const int t = c * 64 + lane;
        const float* xr = x + (size_t)(b * 512 + t) * 1024 + h * 64;
        const float* kr = Kb + (size_t)(b * 512 + t) * 1024 + h * 64;
        float dg = 0.f, dk = 0.f;
#pragma unroll
        for (int d = 0; d < 64; d += 4) {
            float4 xv = *reinterpret_cast<const float4*>(xr + d);
            float4 kv = *reinterpret_cast<const float4*>(kr + d);
            dg += xv.x * gww[d] + xv.y * gww[d + 1] + xv.z * gww[d + 2] + xv.w * gww[d + 3];
            dk += kv.x * sww[d] + kv.y * sww[d + 1] + kv.z * sww[d + 2] + kv.w * sww[d + 3];
        }
        const float g = sigmoidf_(dg + gwb);
        float lg = logf(fmaxf(g, 1e-6f));
        float ps = lg;
#pragma unroll
        for (int off = 1; off < 64; off <<= 1) {
            float v = __shfl_up(ps, off, 64);
            if (lane >= off) ps += v;
        }
        const float lsum = carry + ps;
        const float lclip = fminf(fmaxf(lsum, -30.f), 30.f);
        const float Gc = expf(lclip) + 1e-6f;
        const float z = dk + swb;
        const float R = z * sigmoidf_(z);
        gc[bh * 512 + t] = Gc;
        ab[bh * 512 + t] = R / Gc;
        carry += __shfl(ps, 63, 64);
    }
}

// ---------------------------------------------------------------------------
// Chunk state update: dS[bh][j][d][e] = sum_{tau in chunk j} w[tau]*K'[tau][d]*V'[tau][e]
// MODE 0: K' = a*K, V' = x.   MODE 1: K' = sigmoid(C2*c), V' = x[tau+1]-O1[tau].
// grid (8, 32) = (chunk, bh), 256 threads, 32 MFMA/block.
// ---------------------------------------------------------------------------
template <int MODE>
__global__ __launch_bounds__(256) void attn_dS(const float* __restrict__ x,
                                               const float* __restrict__ Kb,
                                               const float* __restrict__ C2,
                                               const float* __restrict__ O1,
                                               const float* __restrict__ ab,
                                               float* __restrict__ dS) {
    const int j = blockIdx.x, bh = blockIdx.y;
    const int b = bh >> 4, h = bh & 15;
    const int c0 = j * 64;
    const int tid = threadIdx.x;
    const int wave = tid >> 6, lane = tid & 63;
    const int l15 = lane & 15, lq = lane >> 4;

    __shared__ ushort_t AT[64][72];  // [d][tau]
    __shared__ ushort_t BT[64][72];  // [e][tau]

    const size_t base = (size_t)(b * 512) * 1024 + h * 64;

    for (int idx = tid; idx < 1024; idx += 256) {
        const int cc = idx >> 4;
        const int c4 = (idx & 15) << 2;
        const int tau = c0 + cc;
        float4 kv, vv;
        if (MODE == 0) {
            kv = *reinterpret_cast<const float4*>(&Kb[base + (size_t)tau * 1024 + c4]);
            const float a = ab[bh * 512 + tau];
            kv.x *= a; kv.y *= a; kv.z *= a; kv.w *= a;
            vv = *reinterpret_cast<const float4*>(&x[base + (size_t)tau * 1024 + c4]);
        } else {
            if (tau <= 510) {
                float4 cv = *reinterpret_cast<const float4*>(&C2[base + (size_t)tau * 1024 + c4]);
                kv.x = sigmoidf_(cv.x * 6.25e-4f);
                kv.y = sigmoidf_(cv.y * 6.25e-4f);
                kv.z = sigmoidf_(cv.z * 6.25e-4f);
                kv.w = sigmoidf_(cv.w * 6.25e-4f);
                float4 xv = *reinterpret_cast<const float4*>(&x[base + (size_t)(tau + 1) * 1024 + c4]);
                float4 ov = *reinterpret_cast<const float4*>(&O1[base + (size_t)tau * 1024 + c4]);
                vv.x = xv.x - ov.x; vv.y = xv.y - ov.y; vv.z = xv.z - ov.z; vv.w = xv.w - ov.w;
            } else {
                kv.x = kv.y = kv.z = kv.w = 0.f;
                vv.x = vv.y = vv.z = vv.w = 0.f;
            }
        }
        AT[c4 + 0][cc] = f2bf(kv.x); AT[c4 + 1][cc] = f2bf(kv.y);
        AT[c4 + 2][cc] = f2bf(kv.z); AT[c4 + 3][cc] = f2bf(kv.w);
        BT[c4 + 0][cc] = f2bf(vv.x); BT[c4 + 1][cc] = f2bf(vv.y);
        BT[c4 + 2][cc] = f2bf(vv.z); BT[c4 + 3][cc] = f2bf(vv.w);
    }
    __syncthreads();

    f32x4 acc[4];
#pragma unroll
    for (int n = 0; n < 4; ++n) acc[n] = (f32x4){0.f, 0.f, 0.f, 0.f};

#pragma unroll
    for (int kk = 0; kk < 64; kk += 32) {
        bf16x8 a = *reinterpret_cast<const bf16x8*>(&AT[16 * wave + l15][kk + 8 * lq]);
#pragma unroll
        for (int n = 0; n < 4; ++n) {
            bf16x8 bb = *reinterpret_cast<const bf16x8*>(&BT[16 * n + l15][kk + 8 * lq]);
            acc[n] = __builtin_amdgcn_mfma_f32_16x16x32_bf16(a, bb, acc[n], 0, 0, 0);
        }
    }

    float* o = dS + (size_t)(bh * 8 + j) * 4096;
#pragma unroll
    for (int n = 0; n < 4; ++n)
#pragma unroll
        for (int r = 0; r < 4; ++r)
            o[(16 * wave + 4 * lq + r) * 64 + 16 * n + l15] = acc[n][r];
}

// ---------------------------------------------------------------------------
// Exclusive prefix over chunks; emits S^T (bf16, [e][d] layout) per chunk.
// 512 blocks * 256 threads; thread owns one (bh,d,e).
// ---------------------------------------------------------------------------
__global__ __launch_bounds__(256) void prefix_kernel(const float* __restrict__ dS,
                                                     ushort_t* __restrict__ ST) {
    const int gid = blockIdx.x * 256 + threadIdx.x;   // 0..131071
    const int bh = gid >> 12;
    const int rem = gid & 4095;
    const int d = rem >> 6, e = rem & 63;             // e fast -> coalesced reads
    float s = 0.f;
#pragma unroll
    for (int j = 0; j < 8; ++j) {
        ST[(size_t)(bh * 8 + j) * 4096 + e * 64 + d] = f2bf(s);
        s += dS[(size_t)(bh * 8 + j) * 4096 + d * 64 + e];
    }
}

// ---------------------------------------------------------------------------
// Output kernel: per (bh, rt):
//   acc = Q @ S_rt  +  (mask(Q K'^T) [*a]) @ V'
// MODE 0: Out=O1 = Gc * acc.
// MODE 1: Out=Yt: Yt[t'+1] = O1[t'+1] + acc[t'];  Yt[0] = O1[0].
// grid (8, 32), 256 threads, 96 MFMA/block.
// ---------------------------------------------------------------------------
template <int MODE>
__global__ __launch_bounds__(256) void attn_out(const float* __restrict__ x,
                                                const float* __restrict__ Qb,
                                                const float* __restrict__ Kb,
                                                const float* __restrict__ C2,
                                                const float* __restrict__ O1,
                                                const float* __restrict__ gc,
                                                const float* __restrict__ ab,
                                                const ushort_t* __restrict__ ST,
                                                float* __restrict__ Out) {
    const int rt = blockIdx.x, bh = blockIdx.y;
    const int b = bh >> 4, h = bh & 15;
    const int r0 = rt * 64;
    const int tid = threadIdx.x;
    const int wave = tid >> 6, lane = tid & 63;
    const int l15 = lane & 15, lq = lane >> 4;

    __shared__ ushort_t Qs[64][72];   // [t][d]
    __shared__ ushort_t Ks[64][72];   // [c][d]
    __shared__ ushort_t VT[64][72];   // [e][tau]
    __shared__ ushort_t Ps[64][72];   // [t][c]
    __shared__ float av[64];

    const size_t base = (size_t)(b * 512) * 1024 + h * 64;

    // stage Q (natural), K' (natural), V'^T (transposed)
    for (int idx = tid; idx < 1024; idx += 256) {
        const int rr = idx >> 4;
        const int c4 = (idx & 15) << 2;
        float4 qv = *reinterpret_cast<const float4*>(&Qb[base + (size_t)(r0 + rr) * 1024 + c4]);
        if (MODE == 1) {
            qv.x = (qv.x < 0.f ? qv.x : 0.02f * qv.x) * 0.125f;
            qv.y = (qv.y < 0.f ? qv.y : 0.02f * qv.y) * 0.125f;
            qv.z = (qv.z < 0.f ? qv.z : 0.02f * qv.z) * 0.125f;
            qv.w = (qv.w < 0.f ? qv.w : 0.02f * qv.w) * 0.125f;
        }
        Qs[rr][c4 + 0] = f2bf(qv.x); Qs[rr][c4 + 1] = f2bf(qv.y);
        Qs[rr][c4 + 2] = f2bf(qv.z); Qs[rr][c4 + 3] = f2bf(qv.w);

        const int tau = r0 + rr;
        float4 kv, vv;
        if (MODE == 0) {
            kv = *reinterpret_cast<const float4*>(&Kb[base + (size_t)tau * 1024 + c4]);
            vv = *reinterpret_cast<const float4*>(&x[base + (size_t)tau * 1024 + c4]);
        } else {
            if (tau <= 510) {
                float4 cv = *reinterpret_cast<const float4*>(&C2[base + (size_t)tau * 1024 + c4]);
                kv.x = sigmoidf_(cv.x * 6.25e-4f);
                kv.y = sigmoidf_(cv.y * 6.25e-4f);
                kv.z = sigmoidf_(cv.z * 6.25e-4f);
                kv.w = sigmoidf_(cv.w * 6.25e-4f);
                float4 xv = *reinterpret_cast<const float4*>(&x[base + (size_t)(tau + 1) * 1024 + c4]);
                float4 ov = *reinterpret_cast<const float4*>(&O1[base + (size_t)tau * 1024 + c4]);
                vv.x = xv.x - ov.x; vv.y = xv.y - ov.y; vv.z = xv.z - ov.z; vv.w = xv.w - ov.w;
            } else {
                kv.x = kv.y = kv.z = kv.w = 0.f;
                vv.x = vv.y = vv.z = vv.w = 0.f;
            }
        }
        Ks[rr][c4 + 0] = f2bf(kv.x); Ks[rr][c4 + 1] = f2bf(kv.y);
        Ks[rr][c4 + 2] = f2bf(kv.z); Ks[rr][c4 + 3] = f2bf(kv.w);
        VT[c4 + 0][rr] = f2bf(vv.x); VT[c4 + 1][rr] = f2bf(vv.y);
        VT[c4 + 2][rr] = f2bf(vv.z); VT[c4 + 3][rr] = f2bf(vv.w);
    }
    if (MODE == 0 && tid < 64) av[tid] = ab[bh * 512 + r0 + tid];
    __syncthreads();

    // scores: S[t][c], wave owns t-tile [16w,16w+16)
    f32x4 sacc[4];
#pragma unroll
    for (int n = 0; n < 4; ++n) sacc[n] = (f32x4){0.f, 0.f, 0.f, 0.f};
#pragma unroll
    for (int kk = 0; kk < 64; kk += 32) {
        bf16x8 a = *reinterpret_cast<const bf16x8*>(&Qs[16 * wave + l15][kk + 8 * lq]);
#pragma unroll
        for (int n = 0; n < 4; ++n) {
            bf16x8 bb = *reinterpret_cast<const bf16x8*>(&Ks[16 * n + l15][kk + 8 * lq]);
            sacc[n] = __builtin_amdgcn_mfma_f32_16x16x32_bf16(a, bb, sacc[n], 0, 0, 0);
        }
    }
    // mask, scale, write P to LDS (bf16)
#pragma unroll
    for (int n = 0; n < 4; ++n) {
        const int c = 16 * n + l15;
#pragma unroll
        for (int r = 0; r < 4; ++r) {
            const int t = 16 * wave + 4 * lq + r;
            float sv = sacc[n][r];
            if (MODE == 0) sv *= av[c];
            if (c > t) sv = 0.f;
            Ps[t][c] = f2bf(sv);
        }
    }
    __syncthreads();

    // acc[t][e] = Q @ S_rt (global bf16 B-frag) + P @ V
    const ushort_t* Sg = ST + (size_t)(bh * 8 + rt) * 4096;
    f32x4 acc[4];
#pragma unroll
    for (int n = 0; n < 4; ++n) acc[n] = (f32x4){0.f, 0.f, 0.f, 0.f};
#pragma unroll
    for (int kk = 0; kk < 64; kk += 32) {
        bf16x8 a = *reinterpret_cast<const bf16x8*>(&Qs[16 * wave + l15][kk + 8 * lq]);
        bf16x8 p = *reinterpret_cast<const bf16x8*>(&Ps[16 * wave + l15][kk + 8 * lq]);
#pragma unroll
        for (int n = 0; n < 4; ++n) {
            bf16x8 sb = *reinterpret_cast<const bf16x8*>(Sg + (16 * n + l15) * 64 + kk + 8 * lq);
            acc[n] = __builtin_amdgcn_mfma_f32_16x16x32_bf16(a, sb, acc[n], 0, 0, 0);
            bf16x8 vb = *reinterpret_cast<const bf16x8*>(&VT[16 * n + l15][kk + 8 * lq]);
            acc[n] = __builtin_amdgcn_mfma_f32_16x16x32_bf16(p, vb, acc[n], 0, 0, 0);
        }
    }

    if (MODE == 0) {
#pragma unroll
        for (int r = 0; r < 4; ++r) {
            const int t = 16 * wave + 4 * lq + r;
            const float gcr = gc[bh * 512 + r0 + t];
#pragma unroll
            for (int n = 0; n < 4; ++n)
                Out[base + (size_t)(r0 + t) * 1024 + 16 * n + l15] = gcr * acc[n][r];
        }
    } else {
#pragma unroll
        for (int r = 0; r < 4; ++r) {
            const int tp = r0 + 16 * wave + 4 * lq + r;
            if (tp <= 510) {
#pragma unroll
                for (int n = 0; n < 4; ++n)
                    Out[base + (size_t)(tp + 1) * 1024 + 16 * n + l15] =
                        O1[base + (size_t)(tp + 1) * 1024 + 16 * n + l15] + acc[n][r];
            }
        }
        if (rt == 0 && tid < 64)
            Out[base + tid] = O1[base + tid];
    }
}

// ---------------------------------------------------------------------------
extern "C" void kernel_launch(void* const* d_in, const int* in_sizes, int n_in,
                              void* d_out, int out_size, void* d_ws, size_t ws_size,
                              hipStream_t stream) {
    const float* x   = (const float*)d_in[0];
    const float* q1w = (const float*)d_in[1];
    const float* q1b = (const float*)d_in[2];
    const float* k1w = (const float*)d_in[3];
    const float* k1b = (const float*)d_in[4];
    const float* k2w = (const float*)d_in[5];
    const float* k2b = (const float*)d_in[6];
    const float* gww = (const float*)d_in[7];
    const float* gwb = (const float*)d_in[8];
    const float* sww = (const float*)d_in[9];
    const float* swb = (const float*)d_in[10];
    const float* cpw = (const float*)d_in[11];
    const float* cpb = (const float*)d_in[12];
    float* out = (float*)d_out;

    float* ws = (float*)d_ws;
    float* Q   = ws;                        // 1M floats
    float* K   = ws + 1048576;              // 1M
    float* C2  = ws + 2097152;              // 1M
    float* O1  = ws + 3145728;              // 1M
    float* Yt  = ws + 4194304;              // 1M
    float* gcb = ws + 5242880;              // 16K
    float* abb = ws + 5259264;              // 16K
    float* dS  = ws + 5275648;              // 1M floats (32*8*4096)
    ushort_t* STb = (ushort_t*)(ws + 6324224);    // 1M ushorts = 512K floats
    ushort_t* xb  = (ushort_t*)(ws + 6848512);    // 1M ushorts each below
    ushort_t* wqb = (ushort_t*)(ws + 7372800);
    ushort_t* wkb = (ushort_t*)(ws + 7897088);
    ushort_t* wcb = (ushort_t*)(ws + 8421376);
    ushort_t* wpb = (ushort_t*)(ws + 8945664);
    ushort_t* ytb = (ushort_t*)(ws + 9469952);
    // end: 9,994,240 floats = 40.0 MB

    cvt5<<<2560, 256, 0, stream>>>(x, q1w, k1w, k2w, cpw, xb, wqb, wkb, wcb, wpb);
    gemm_mfma<<<dim3(16, 16, 3), 256, 0, stream>>>(xb, wqb, wkb, wcb, q1b, k1b, k2b, Q, K, C2);
    scan_kernel<<<32, 64, 0, stream>>>(x, K, gww, gwb, sww, swb, gcb, abb);

    attn_dS<0><<<dim3(8, 32), 256, 0, stream>>>(x, K, C2, O1, abb, dS);
    prefix_kernel<<<512, 256, 0, stream>>>(dS, STb);
    attn_out<0><<<dim3(8, 32), 256, 0, stream>>>(x, Q, K, C2, O1, gcb, abb, STb, O1);

    attn_dS<1><<<dim3(8, 32), 256, 0, stream>>>(x, K, C2, O1, abb, dS);
    prefix_kernel<<<512, 256, 0, stream>>>(dS, STb);
    attn_out<1><<<dim3(8, 32), 256, 0, stream>>>(x, Q, K, C2, O1, gcb, abb, STb, Yt);

    cvt1<<<512, 256, 0, stream>>>(Yt, ytb);
    gemm_mfma<<<dim3(16, 16, 1), 256, 0, stream>>>(ytb, wpb, wpb, wpb, cpb, cpb, cpb, out, out, out);
}